// Round 15
// baseline (161.478 us; speedup 1.0000x reference)
//
#include <hip/hip_runtime.h>

// LR_PINN_phase2_midout: fused 4-stage tiny MLP, N=262144, H=256, R=32.
// R15 = R14 + 4-way batched reciprocal (shallow tree) for the inv() calls.
// Plateau analysis (R11/R12/R14 all ~76 us across 4wave*4stream, 8wave*2stream
// configs; VALUBusy+MfmaUtil ~= 100%): issue port saturated, trans ops at
// ~16 cyc/wave-instr dominate (131k of ~172k cyc/SIMD). R8's 8-way tree
// failed on chain depth at 4 waves; this is the 4-way SHALLOW tree
// (exp->mul->rcp->mul, depth ~5) at 8 waves/SIMD: per 4 el, 4 trans + 17 reg
// vs 8 trans + 8 reg. Inputs clamped y<=30 so the 4-product stays finite
// (e<=2^30, prod<2^122; clamp abs err <= 9.3e-10).
//
// Kept from R14: inv-feeding (inv=rcp(exp2(y)+1), -2 folded into ctf & ew,
// rowsum-initialized accs, ewsum epilogue; absmax 7.3e-4 HW-verified),
// rwf in global scratch (L2-resident; LDS 52 KB -> 2 blocks/CU -> 8 waves/
// SIMD), mfma_f32_16x16x16f16 layout-closed chain, fragment-ordered
// conflict-free LDS/global reads, dual streams, 16 unroll-1 bodies,
// v_cvt_pkrtz packing, tanh scale 2*log2e folded at staging.

typedef _Float16 half4_t __attribute__((ext_vector_type(4)));
typedef __fp16   fp16x2  __attribute__((ext_vector_type(2)));
typedef float    float4_t __attribute__((ext_vector_type(4)));

#define TANH_SCALE 2.885390081777927f  // 2*log2(e); exp2(S*x) == exp(2x)
#define MFMA16 __builtin_amdgcn_mfma_f32_16x16x16f16
#define NFRAG (3 * 16 * 2 * 64)        // 6144 half4 entries per matrix

namespace {

struct alignas(16) Smem {
  // entry index e = ((k*16+t)*2+sel)*64+lane ; one half4 (8 B) per lane.
  half4_t ctf[NFRAG];               // 48 KB: -2 * alpha * Ct[sel*16+m][16t+4q+jj]
  float w0[256], w1[256], bb[256];  // pre-scaled by S
  float ew[256];                    // -2 * end_w
  float rsC[3 * 32];                // rowsums: sum_j alpha*Ct[r][j]
};

__device__ __forceinline__ half4_t pack4(float4_t v) {
  union { fp16x2 f2[2]; half4_t h4; } u;
  u.f2[0] = __builtin_amdgcn_cvt_pkrtz(v.x, v.y);
  u.f2[1] = __builtin_amdgcn_cvt_pkrtz(v.z, v.w);
  return u.h4;
}

// inv_i = 1/(1+exp2(min(y_i,30))) for 4 elements via ONE rcp (shallow tree:
// exp -> mul -> rcp -> mul -> mul, depth ~5). tanh(x) = 1 - 2*inv; the -2/+1
// live in the weights/rowsums. Clamp y<=30: e<=2^30, 4-product < 2^122
// (finite); abs clamp error <= 2^-30, far below fp16 pack noise.
__device__ __forceinline__ float4_t inv4f(float4_t v) {
  const float a0 = __builtin_amdgcn_exp2f(fminf(v.x, 30.0f)) + 1.0f;
  const float a1 = __builtin_amdgcn_exp2f(fminf(v.y, 30.0f)) + 1.0f;
  const float a2 = __builtin_amdgcn_exp2f(fminf(v.z, 30.0f)) + 1.0f;
  const float a3 = __builtin_amdgcn_exp2f(fminf(v.w, 30.0f)) + 1.0f;
  const float p01 = a0 * a1, p23 = a2 * a3;
  const float rd = __builtin_amdgcn_rcpf(p01 * p23);
  const float r01 = rd * p23, r23 = rd * p01;  // 1/p01, 1/p23
  float4_t r;
  r.x = r01 * a1; r.y = r01 * a0;
  r.z = r23 * a3; r.w = r23 * a2;
  return r;
}

__device__ __forceinline__ half4_t inv4(float4_t v) { return pack4(inv4f(v)); }

// ---- pre-kernel: stage rwf fragments (S-prescaled fp16) into d_ws ----
__global__ __launch_bounds__(1024) void stage_rwf(
    const float* __restrict__ r0, const float* __restrict__ r1,
    const float* __restrict__ r2, half4_t* __restrict__ ws)
{
  const int e = blockIdx.x * 1024 + threadIdx.x;
  if (e >= NFRAG) return;
  const int lane_ = e & 63;
  const int sel   = (e >> 6) & 1;
  const int t_    = (e >> 7) & 15;
  const int k_    = e >> 11;
  const int m_ = lane_ & 15, q_ = lane_ >> 4;
  const float* rk = (k_ == 0) ? r0 : (k_ == 1) ? r1 : r2;
  const int j = 16 * t_ + m_;
  const int rr = sel * 16 + 4 * q_;
  half4_t v;
  v.x = (_Float16)(rk[j * 32 + rr + 0] * TANH_SCALE);
  v.y = (_Float16)(rk[j * 32 + rr + 1] * TANH_SCALE);
  v.z = (_Float16)(rk[j * 32 + rr + 2] * TANH_SCALE);
  v.w = (_Float16)(rk[j * 32 + rr + 3] * TANH_SCALE);
  ws[e] = v;
}

__global__ __launch_bounds__(1024)
__attribute__((amdgpu_waves_per_eu(8, 8)))
void pinn_fused(
    const float* __restrict__ xg, const float* __restrict__ tg,
    const float* __restrict__ sw, const float* __restrict__ sb,
    const float* __restrict__ ewp, const float* __restrict__ ebp,
    const float* __restrict__ c0, const float* __restrict__ c1,
    const float* __restrict__ c2, const float* __restrict__ a0,
    const float* __restrict__ a1, const float* __restrict__ a2,
    const half4_t* __restrict__ rwg, float* __restrict__ out, int n)
{
  __shared__ Smem sm;
  const int tid = threadIdx.x;

  // ---- stage ctf (with -2*alpha folded) into fragment-ordered LDS ----
  for (int e = tid; e < NFRAG; e += 1024) {
    const int lane_ = e & 63;
    const int sel   = (e >> 6) & 1;
    const int t_    = (e >> 7) & 15;
    const int k_    = e >> 11;
    const int m_ = lane_ & 15, q_ = lane_ >> 4;
    const float* ck = (k_ == 0) ? c0 : (k_ == 1) ? c1 : c2;
    const float* ak = (k_ == 0) ? a0 : (k_ == 1) ? a1 : a2;
    const int r = sel * 16 + m_;
    const float av = ak[r] * -2.0f;
    const int j0 = 16 * t_ + 4 * q_;
    half4_t v;
    v.x = (_Float16)(ck[(j0 + 0) * 32 + r] * av);
    v.y = (_Float16)(ck[(j0 + 1) * 32 + r] * av);
    v.z = (_Float16)(ck[(j0 + 2) * 32 + r] * av);
    v.w = (_Float16)(ck[(j0 + 3) * 32 + r] * av);
    sm.ctf[e] = v;
  }
  if (tid < 256) {
    sm.w0[tid] = sw[2 * tid] * TANH_SCALE;
    sm.w1[tid] = sw[2 * tid + 1] * TANH_SCALE;
    sm.bb[tid] = sb[tid] * TANH_SCALE;
    sm.ew[tid] = ewp[tid] * -2.0f;              // fold -2
  }
  __syncthreads();

  // ---- rowsums rsC[k][r] = sum_j alpha*Ct[r][j] = -0.5 * sum(ctf frags) ----
  if (tid < 96) {
    const int k_ = tid >> 5, r = tid & 31;
    const int sel = r >> 4, mm = r & 15;
    float s = 0.0f;
    for (int t = 0; t < 16; ++t)
      for (int qq = 0; qq < 4; ++qq) {
        const half4_t v = sm.ctf[((k_ * 16 + t) * 2 + sel) * 64 + 16 * qq + mm];
        s += (float)v.x + (float)v.y + (float)v.z + (float)v.w;
      }
    sm.rsC[k_ * 32 + r] = -0.5f * s;
  }
  __syncthreads();

  const int wave = tid >> 6;
  const int lane = tid & 63;
  const int m = lane & 15;   // point index (MFMA col / A-row / B-col)
  const int q = lane >> 4;   // quad
  const int wo = 4 * q;      // j = 16t + 4q + jj
  const float ebv = ebp[0];
  const int tiles = n >> 4;

  // per-lane ewsum: out = sum(ew) + sum((-2ew)*inv); sm.ew = -2*ew
  float ewsum = 0.0f;
  for (int t = 0; t < 16; ++t) {
    const float4_t e4 = *(const float4_t*)&sm.ew[t * 16 + wo];
    ewsum += e4.x + e4.y + e4.z + e4.w;
  }
  ewsum *= -0.5f;

  const float4_t z4 = {0.f, 0.f, 0.f, 0.f};  // hoisted MFMA C-operand zero

#pragma unroll 1
  for (int g = (blockIdx.x * 16 + wave) * 2; g < tiles; g += 16384) {
    const int n0 = g * 16;
    const int n1 = n0 + 16;
    const float xm0 = xg[n0 + m], tm0 = tg[n0 + m];
    const float xm1 = xg[n1 + m], tm1 = tg[n1 + m];

    // ---- phase0 fused with GEMM1(k=0); accs init with rowsums(0) ----
    const float4_t rs00 = *(const float4_t*)&sm.rsC[wo];
    const float4_t rs01 = *(const float4_t*)&sm.rsC[16 + wo];
    float4_t a00 = rs00, a01 = rs01, a10 = rs00, a11 = rs01;
    const half4_t* cp0 = &sm.ctf[lane];
#pragma unroll 1
    for (int t = 0; t < 16; ++t) {
      const int cb = t * 16 + wo;
      const float4_t w0v = *(const float4_t*)&sm.w0[cb];
      const float4_t w1v = *(const float4_t*)&sm.w1[cb];
      const float4_t bv  = *(const float4_t*)&sm.bb[cb];
      float4_t z0, z1;
      z0.x = fmaf(xm0, w0v.x, fmaf(tm0, w1v.x, bv.x));
      z1.x = fmaf(xm1, w0v.x, fmaf(tm1, w1v.x, bv.x));
      z0.y = fmaf(xm0, w0v.y, fmaf(tm0, w1v.y, bv.y));
      z1.y = fmaf(xm1, w0v.y, fmaf(tm1, w1v.y, bv.y));
      z0.z = fmaf(xm0, w0v.z, fmaf(tm0, w1v.z, bv.z));
      z1.z = fmaf(xm1, w0v.z, fmaf(tm1, w1v.z, bv.z));
      z0.w = fmaf(xm0, w0v.w, fmaf(tm0, w1v.w, bv.w));
      z1.w = fmaf(xm1, w0v.w, fmaf(tm1, w1v.w, bv.w));
      const half4_t h0 = inv4(z0);
      const half4_t h1 = inv4(z1);
      const half4_t cA = cp0[0], cB = cp0[64];
      a00 = MFMA16(cA, h0, a00, 0, 0, 0);
      a10 = MFMA16(cA, h1, a10, 0, 0, 0);
      a01 = MFMA16(cB, h0, a01, 0, 0, 0);
      a11 = MFMA16(cB, h1, a11, 0, 0, 0);
      cp0 += 128;
    }

#pragma unroll 1
    for (int k = 0; k < 2; ++k) {
      // acc holds true P (rowsum init); pack as next B-frag.
      const half4_t pA0 = pack4(a00), pB0 = pack4(a01);
      const half4_t pA1 = pack4(a10), pB1 = pack4(a11);
      const float4_t rsA = *(const float4_t*)&sm.rsC[(k + 1) * 32 + wo];
      const float4_t rsB = *(const float4_t*)&sm.rsC[(k + 1) * 32 + 16 + wo];
      float4_t n00 = rsA, n01 = rsB, n10 = rsA, n11 = rsB;
      const half4_t* rp = &rwg[k * 2048 + lane];   // global, L2-resident
      const half4_t* cp = &sm.ctf[(k + 1) * 2048 + lane];
#pragma unroll 1
      for (int t = 0; t < 16; ++t) {
        const half4_t rA = rp[0], rB = rp[64];
        const half4_t cA = cp[0], cB = cp[64];
        float4_t u0 = MFMA16(rA, pA0, z4, 0, 0, 0);
        float4_t u1 = MFMA16(rA, pA1, z4, 0, 0, 0);
        u0 = MFMA16(rB, pB0, u0, 0, 0, 0);
        u1 = MFMA16(rB, pB1, u1, 0, 0, 0);
        const half4_t h0 = inv4(u0);
        const half4_t h1 = inv4(u1);
        n00 = MFMA16(cA, h0, n00, 0, 0, 0);
        n10 = MFMA16(cA, h1, n10, 0, 0, 0);
        n01 = MFMA16(cB, h0, n01, 0, 0, 0);
        n11 = MFMA16(cB, h1, n11, 0, 0, 0);
        rp += 128; cp += 128;
      }
      a00 = n00; a01 = n01; a10 = n10; a11 = n11;
    }

    // ---- k=2: GEMM2(2) fused with the end_w dot; ssum init = ewsum ----
    float ssum0 = ewsum, ssum1 = ewsum;
    {
      const half4_t pA0 = pack4(a00), pB0 = pack4(a01);
      const half4_t pA1 = pack4(a10), pB1 = pack4(a11);
      const half4_t* rp = &rwg[2 * 2048 + lane];
#pragma unroll 1
      for (int t = 0; t < 16; ++t) {
        const half4_t rA = rp[0], rB = rp[64];
        const float4_t ev = *(const float4_t*)&sm.ew[t * 16 + wo];  // -2*ew
        float4_t u0 = MFMA16(rA, pA0, z4, 0, 0, 0);
        float4_t u1 = MFMA16(rA, pA1, z4, 0, 0, 0);
        u0 = MFMA16(rB, pB0, u0, 0, 0, 0);
        u1 = MFMA16(rB, pB1, u1, 0, 0, 0);
        const float4_t i0 = inv4f(u0);
        const float4_t i1 = inv4f(u1);
        ssum0 = fmaf(ev.x, i0.x, ssum0);
        ssum1 = fmaf(ev.x, i1.x, ssum1);
        ssum0 = fmaf(ev.y, i0.y, ssum0);
        ssum1 = fmaf(ev.y, i1.y, ssum1);
        ssum0 = fmaf(ev.z, i0.z, ssum0);
        ssum1 = fmaf(ev.z, i1.z, ssum1);
        ssum0 = fmaf(ev.w, i0.w, ssum0);
        ssum1 = fmaf(ev.w, i1.w, ssum1);
        rp += 128;
      }
    }

    // reduce each stream's partial dot over the 4 quads
    ssum0 += __shfl_xor(ssum0, 16);
    ssum0 += __shfl_xor(ssum0, 32);
    ssum1 += __shfl_xor(ssum1, 16);
    ssum1 += __shfl_xor(ssum1, 32);
    if (lane < 16) {
      out[n0 + m] = ssum0 + ebv;
      out[n1 + m] = ssum1 + ebv;
    }
  }
}

}  // namespace

extern "C" void kernel_launch(void* const* d_in, const int* in_sizes, int n_in,
                              void* d_out, int out_size, void* d_ws, size_t ws_size,
                              hipStream_t stream) {
  const float* xg  = (const float*)d_in[0];
  const float* tg  = (const float*)d_in[1];
  const float* sw  = (const float*)d_in[2];
  const float* sb  = (const float*)d_in[3];
  const float* ewp = (const float*)d_in[4];
  const float* ebp = (const float*)d_in[5];
  const float* c0  = (const float*)d_in[6];
  const float* c1  = (const float*)d_in[7];
  const float* c2  = (const float*)d_in[8];
  const float* r0  = (const float*)d_in[9];
  const float* r1  = (const float*)d_in[10];
  const float* r2  = (const float*)d_in[11];
  const float* a0  = (const float*)d_in[12];
  const float* a1  = (const float*)d_in[13];
  const float* a2  = (const float*)d_in[14];
  float* outp = (float*)d_out;
  half4_t* ws = (half4_t*)d_ws;   // 48 KB of rwf fragments

  const int n = in_sizes[0];  // 262144

  // stage rwf into d_ws (same stream: ordered before the main kernel)
  stage_rwf<<<(NFRAG + 1023) / 1024, 1024, 0, stream>>>(r0, r1, r2, ws);

  pinn_fused<<<512, 1024, 0, stream>>>(xg, tg, sw, sb, ewp, ebp,
                                       c0, c1, c2, a0, a1, a2,
                                       ws, outp, n);
}

// Round 16
// 141.313 us; speedup vs baseline: 1.1427x; 1.1427x over previous
//
#include <hip/hip_runtime.h>

// LR_PINN_phase2_midout: fused 4-stage tiny MLP, N=262144, H=256, R=32.
// R16 = R11 (best wall, 75.4 us: all-LDS weights, QUAD streams, 4 waves/SIMD)
//     + inv-feeding (R13-measured busy cut, never combined with quad streams):
//   inv = rcp(exp2(y)+1) replaces tanh = fma(-2,inv,1);
//   -2 folded into ctf & ew; GEMM1 accs init with rowsums
//   sum_j(alpha*Ct[r][j]); epilogue ssum init with ewsum.
//   Numerics HW-verified R8/R13/R14: absmax 7.3e-4 < 1.52e-3 threshold.
// R15 post-mortem closed the batched-rcp line for good (2nd regression):
// with multi-wave overlap the trans pipe is NOT the pole; trading trans for
// regular ops loads the busier pipe. Only net-issue-cycle cuts pay.
//
// Kept from R11: mfma_f32_16x16x16f16 layout-closed chain (C/D row=4q+reg
// == next B-frag k=4q+jj; zero LDS round-trips/barriers in steady state),
// fragment-ordered conflict-free LDS (base+lane*8), strict #pragma unroll 1
// t-loops, phase-grouped quad-stream MFMAs (4 independent chains/body),
// v_cvt_pkrtz packing, tanh scale 2*log2e folded into w0/w1/bb and rwf.

typedef _Float16 half4_t __attribute__((ext_vector_type(4)));
typedef __fp16   fp16x2  __attribute__((ext_vector_type(2)));
typedef float    float4_t __attribute__((ext_vector_type(4)));

#define TANH_SCALE 2.885390081777927f  // 2*log2(e); exp2(S*x) == exp(2x)
#define MFMA16 __builtin_amdgcn_mfma_f32_16x16x16f16

namespace {

struct alignas(16) Smem {
  // entry index e = ((k*16+t)*2+sel)*64+lane ; one half4 (8 B) per lane.
  half4_t ctf[3 * 16 * 2 * 64];  // 48 KB: -2 * alpha * Ct[sel*16+m][16t+4q+jj]
  half4_t rwf[3 * 16 * 2 * 64];  // 48 KB:  S * R[16t+m][sel*16+4q+jj]
  float w0[256], w1[256], bb[256];  // pre-scaled by S
  float ew[256];                    // -2 * end_w
  float rsC[3 * 32];                // rowsums: sum_j alpha*Ct[r][j]
};

__device__ __forceinline__ half4_t pack4(float4_t v) {
  union { fp16x2 f2[2]; half4_t h4; } u;
  u.f2[0] = __builtin_amdgcn_cvt_pkrtz(v.x, v.y);
  u.f2[1] = __builtin_amdgcn_cvt_pkrtz(v.z, v.w);
  return u.h4;
}

// inv = 1/(1+exp2(y)); tanh(x) = 1 - 2*inv (the -2/+1 live in weights/sums).
// No clamp: e=inf -> rcp(inf)=0 exact; e->0 -> inv->1 exact.
__device__ __forceinline__ float inv_pre(float y) {
  return __builtin_amdgcn_rcpf(__builtin_amdgcn_exp2f(y) + 1.0f);
}

__device__ __forceinline__ half4_t inv4(float4_t v) {
  float4_t r;
  r.x = inv_pre(v.x); r.y = inv_pre(v.y);
  r.z = inv_pre(v.z); r.w = inv_pre(v.w);
  return pack4(r);
}

__global__ __launch_bounds__(1024)
__attribute__((amdgpu_waves_per_eu(4, 4)))
void pinn_fused(
    const float* __restrict__ xg, const float* __restrict__ tg,
    const float* __restrict__ sw, const float* __restrict__ sb,
    const float* __restrict__ ewp, const float* __restrict__ ebp,
    const float* __restrict__ c0, const float* __restrict__ c1,
    const float* __restrict__ c2, const float* __restrict__ r0,
    const float* __restrict__ r1, const float* __restrict__ r2,
    const float* __restrict__ a0, const float* __restrict__ a1,
    const float* __restrict__ a2, float* __restrict__ out, int n)
{
  __shared__ Smem sm;
  const int tid = threadIdx.x;

  // ---- stage weights into fragment-ordered fp16 LDS (once per block) ----
  for (int e = tid; e < 3 * 16 * 2 * 64; e += 1024) {
    const int lane_ = e & 63;
    const int sel   = (e >> 6) & 1;
    const int t_    = (e >> 7) & 15;
    const int k_    = e >> 11;
    const int m_ = lane_ & 15, q_ = lane_ >> 4;
    const float* ck = (k_ == 0) ? c0 : (k_ == 1) ? c1 : c2;
    const float* rk = (k_ == 0) ? r0 : (k_ == 1) ? r1 : r2;
    const float* ak = (k_ == 0) ? a0 : (k_ == 1) ? a1 : a2;
    {  // Ct frag: A-row r = sel*16+m, cols j = 16t+4q+jj ; fold -2*alpha
      const int r = sel * 16 + m_;
      const float av = ak[r] * -2.0f;
      const int j0 = 16 * t_ + 4 * q_;
      half4_t v;
      v.x = (_Float16)(ck[(j0 + 0) * 32 + r] * av);
      v.y = (_Float16)(ck[(j0 + 1) * 32 + r] * av);
      v.z = (_Float16)(ck[(j0 + 2) * 32 + r] * av);
      v.w = (_Float16)(ck[(j0 + 3) * 32 + r] * av);
      sm.ctf[e] = v;
    }
    {  // R frag: A-row j = 16t+m, cols r = sel*16+4q+jj ; fold tanh scale S
      const int j = 16 * t_ + m_;
      const int rr = sel * 16 + 4 * q_;
      half4_t v;
      v.x = (_Float16)(rk[j * 32 + rr + 0] * TANH_SCALE);
      v.y = (_Float16)(rk[j * 32 + rr + 1] * TANH_SCALE);
      v.z = (_Float16)(rk[j * 32 + rr + 2] * TANH_SCALE);
      v.w = (_Float16)(rk[j * 32 + rr + 3] * TANH_SCALE);
      sm.rwf[e] = v;
    }
  }
  if (tid < 256) {
    sm.w0[tid] = sw[2 * tid] * TANH_SCALE;
    sm.w1[tid] = sw[2 * tid + 1] * TANH_SCALE;
    sm.bb[tid] = sb[tid] * TANH_SCALE;
    sm.ew[tid] = ewp[tid] * -2.0f;              // fold -2
  }
  __syncthreads();

  // ---- rowsums rsC[k][r] = sum_j alpha*Ct[r][j] = -0.5 * sum(ctf frags) ----
  if (tid < 96) {
    const int k_ = tid >> 5, r = tid & 31;
    const int sel = r >> 4, mm = r & 15;
    float s = 0.0f;
    for (int t = 0; t < 16; ++t)
      for (int qq = 0; qq < 4; ++qq) {
        const half4_t v = sm.ctf[((k_ * 16 + t) * 2 + sel) * 64 + 16 * qq + mm];
        s += (float)v.x + (float)v.y + (float)v.z + (float)v.w;
      }
    sm.rsC[k_ * 32 + r] = -0.5f * s;
  }
  __syncthreads();

  const int wave = tid >> 6;
  const int lane = tid & 63;
  const int m = lane & 15;   // point index (MFMA col / A-row / B-col)
  const int q = lane >> 4;   // quad
  const int wo = 4 * q;      // j = 16t + 4q + jj
  const float ebv = ebp[0];
  const int tiles = n >> 4;

  // per-lane ewsum: out = sum(ew)+sum((-2ew)*inv); sm.ew = -2*ew
  float ewsum = 0.0f;
  for (int t = 0; t < 16; ++t) {
    const float4_t e4 = *(const float4_t*)&sm.ew[t * 16 + wo];
    ewsum += e4.x + e4.y + e4.z + e4.w;
  }
  ewsum *= -0.5f;

  const float4_t z4 = {0.f, 0.f, 0.f, 0.f};  // hoisted MFMA C-operand zero

#pragma unroll 1
  for (int g = (blockIdx.x * 16 + wave) * 4; g < tiles; g += 16384) {
    float xm[4], tm[4];
#pragma unroll
    for (int s = 0; s < 4; ++s) {
      xm[s] = xg[(g + s) * 16 + m];
      tm[s] = tg[(g + s) * 16 + m];
    }

    // ---- phase0 fused with GEMM1(k=0); 4 streams, accs init rowsums(0) ----
    const float4_t rs00 = *(const float4_t*)&sm.rsC[wo];
    const float4_t rs01 = *(const float4_t*)&sm.rsC[16 + wo];
    float4_t acc[4][2];
#pragma unroll
    for (int s = 0; s < 4; ++s) { acc[s][0] = rs00; acc[s][1] = rs01; }
    const half4_t* cp0 = &sm.ctf[lane];
#pragma unroll 1
    for (int t = 0; t < 16; ++t) {
      const int cb = t * 16 + wo;
      const float4_t w0v = *(const float4_t*)&sm.w0[cb];
      const float4_t w1v = *(const float4_t*)&sm.w1[cb];
      const float4_t bv  = *(const float4_t*)&sm.bb[cb];
      half4_t h[4];
#pragma unroll
      for (int s = 0; s < 4; ++s) {
        float4_t z;
        z.x = fmaf(xm[s], w0v.x, fmaf(tm[s], w1v.x, bv.x));
        z.y = fmaf(xm[s], w0v.y, fmaf(tm[s], w1v.y, bv.y));
        z.z = fmaf(xm[s], w0v.z, fmaf(tm[s], w1v.z, bv.z));
        z.w = fmaf(xm[s], w0v.w, fmaf(tm[s], w1v.w, bv.w));
        h[s] = inv4(z);
      }
      const half4_t cA = cp0[0], cB = cp0[64];
#pragma unroll
      for (int s = 0; s < 4; ++s) acc[s][0] = MFMA16(cA, h[s], acc[s][0], 0, 0, 0);
#pragma unroll
      for (int s = 0; s < 4; ++s) acc[s][1] = MFMA16(cB, h[s], acc[s][1], 0, 0, 0);
      cp0 += 128;
    }

#pragma unroll 1
    for (int k = 0; k < 2; ++k) {
      // acc holds true P (rowsum init); pack as next B-frag.
      half4_t pf[4][2];
#pragma unroll
      for (int s = 0; s < 4; ++s) {
        pf[s][0] = pack4(acc[s][0]);
        pf[s][1] = pack4(acc[s][1]);
      }
      const float4_t rsA = *(const float4_t*)&sm.rsC[(k + 1) * 32 + wo];
      const float4_t rsB = *(const float4_t*)&sm.rsC[(k + 1) * 32 + 16 + wo];
      float4_t nn[4][2];
#pragma unroll
      for (int s = 0; s < 4; ++s) { nn[s][0] = rsA; nn[s][1] = rsB; }
      const half4_t* rp = &sm.rwf[k * 2048 + lane];
      const half4_t* cp = &sm.ctf[(k + 1) * 2048 + lane];
#pragma unroll 1
      for (int t = 0; t < 16; ++t) {
        const half4_t rA = rp[0], rB = rp[64];
        const half4_t cA = cp[0], cB = cp[64];
        float4_t u[4];
#pragma unroll
        for (int s = 0; s < 4; ++s) u[s] = MFMA16(rA, pf[s][0], z4, 0, 0, 0);
#pragma unroll
        for (int s = 0; s < 4; ++s) u[s] = MFMA16(rB, pf[s][1], u[s], 0, 0, 0);
        half4_t h[4];
#pragma unroll
        for (int s = 0; s < 4; ++s) h[s] = inv4(u[s]);
#pragma unroll
        for (int s = 0; s < 4; ++s) nn[s][0] = MFMA16(cA, h[s], nn[s][0], 0, 0, 0);
#pragma unroll
        for (int s = 0; s < 4; ++s) nn[s][1] = MFMA16(cB, h[s], nn[s][1], 0, 0, 0);
        rp += 128; cp += 128;
      }
#pragma unroll
      for (int s = 0; s < 4; ++s) { acc[s][0] = nn[s][0]; acc[s][1] = nn[s][1]; }
    }

    // ---- k=2: GEMM2(2) fused with the end_w dot; ssum init = ewsum ----
    float ssum[4] = {ewsum, ewsum, ewsum, ewsum};
    {
      half4_t pf[4][2];
#pragma unroll
      for (int s = 0; s < 4; ++s) {
        pf[s][0] = pack4(acc[s][0]);
        pf[s][1] = pack4(acc[s][1]);
      }
      const half4_t* rp = &sm.rwf[2 * 2048 + lane];
#pragma unroll 1
      for (int t = 0; t < 16; ++t) {
        const half4_t rA = rp[0], rB = rp[64];
        const float4_t ev = *(const float4_t*)&sm.ew[t * 16 + wo];  // -2*ew
        float4_t u[4];
#pragma unroll
        for (int s = 0; s < 4; ++s) u[s] = MFMA16(rA, pf[s][0], z4, 0, 0, 0);
#pragma unroll
        for (int s = 0; s < 4; ++s) u[s] = MFMA16(rB, pf[s][1], u[s], 0, 0, 0);
#pragma unroll
        for (int s = 0; s < 4; ++s) {
          ssum[s] = fmaf(ev.x, inv_pre(u[s].x), ssum[s]);
          ssum[s] = fmaf(ev.y, inv_pre(u[s].y), ssum[s]);
          ssum[s] = fmaf(ev.z, inv_pre(u[s].z), ssum[s]);
          ssum[s] = fmaf(ev.w, inv_pre(u[s].w), ssum[s]);
        }
        rp += 128;
      }
    }

    // reduce each stream's partial dot over the 4 quads
#pragma unroll
    for (int s = 0; s < 4; ++s) {
      ssum[s] += __shfl_xor(ssum[s], 16);
      ssum[s] += __shfl_xor(ssum[s], 32);
    }
    if (lane < 16) {
#pragma unroll
      for (int s = 0; s < 4; ++s) out[(g + s) * 16 + m] = ssum[s] + ebv;
    }
  }
}

}  // namespace

extern "C" void kernel_launch(void* const* d_in, const int* in_sizes, int n_in,
                              void* d_out, int out_size, void* d_ws, size_t ws_size,
                              hipStream_t stream) {
  const float* xg  = (const float*)d_in[0];
  const float* tg  = (const float*)d_in[1];
  const float* sw  = (const float*)d_in[2];
  const float* sb  = (const float*)d_in[3];
  const float* ewp = (const float*)d_in[4];
  const float* ebp = (const float*)d_in[5];
  const float* c0  = (const float*)d_in[6];
  const float* c1  = (const float*)d_in[7];
  const float* c2  = (const float*)d_in[8];
  const float* r0  = (const float*)d_in[9];
  const float* r1  = (const float*)d_in[10];
  const float* r2  = (const float*)d_in[11];
  const float* a0  = (const float*)d_in[12];
  const float* a1  = (const float*)d_in[13];
  const float* a2  = (const float*)d_in[14];
  float* outp = (float*)d_out;

  const int n = in_sizes[0];  // 262144

  pinn_fused<<<256, 1024, 0, stream>>>(xg, tg, sw, sb, ewp, ebp,
                                       c0, c1, c2, r0, r1, r2, a0, a1, a2,
                                       outp, n);
}